// Round 13
// baseline (251.489 us; speedup 1.0000x reference)
//
#include <hip/hip_runtime.h>
#include <hip/hip_bf16.h>

// WeightedLoss round 13: packed-fragment grams + DUAL-ACCUMULATOR loss.
// r11/r12's per-thread f16 sim cache spilled 68 MB to scratch both times
// (vector subscripts defeat SROA before unroll; WRITE_SIZE 64 MB, loss stuck
// at 96 us). r2 proved the dual-MFMA-accumulator shape (accS+accG, 128 AGPRs)
// never spills — accumulators live in AGPRs via v_accvgpr, no SROA involved.
// This round: coalesced packed fragments (r11, fixed the 8x line over-read)
// + r2's spill-proof epilogue reading accS/accG directly.
// ws: [0] Obp bf16 packed 4 MB | [4194304] Lnp bf16 packed 2 MB
//     [6291456] sq f32 | [6324224] pos_sums | [6356992] neg_sums
//     [6389760] stats u32[3]

#define B_N 8192
#define NT   64
#define TILE 128
#define NTRI 2080

typedef __attribute__((ext_vector_type(8))) short bf16x8;
typedef __attribute__((ext_vector_type(4))) float f32x4;

__device__ __forceinline__ unsigned fenc(float f) {
    unsigned u = __float_as_uint(f);
    return (u & 0x80000000u) ? ~u : (u | 0x80000000u);
}
__device__ __forceinline__ float fdec(unsigned k) {
    unsigned u = (k & 0x80000000u) ? (k ^ 0x80000000u) : ~k;
    return __uint_as_float(u);
}

// XCD-swizzled upper-tri decode.
__device__ __forceinline__ void tri_decode_swz(int b, int& bi, int& bj) {
    int t = (b & 7) * (NTRI / 8) + (b >> 3);
    int i = 0, rem = t;
    while (rem >= NT - i) { rem -= NT - i; i++; }
    bi = i; bj = i + rem;
}

// ---------------------------------------------------------------- prep ----
// 4 rows/block (one wave per row). Computes sq, normalizes labels, writes
// both matrices in packed fragment order: 16-B slot S=(g*(K/8)+o)*16+r holds
// X[g*16+r][o*8..o*8+7].
__global__ __launch_bounds__(256) void prep_kernel(
    const float* __restrict__ outputs, const float* __restrict__ labels,
    __hip_bfloat16* __restrict__ Obp, __hip_bfloat16* __restrict__ Lnp,
    float* __restrict__ sq, float* __restrict__ pos_sums,
    float* __restrict__ neg_sums, unsigned* __restrict__ stats) {
    int w = threadIdx.x >> 6, lane = threadIdx.x & 63;
    int r = blockIdx.x * 4 + w;
    int g = r >> 4, rr = r & 15;

    f32x4 v = ((const f32x4*)outputs)[r * 64 + lane];
    float s = v[0]*v[0] + v[1]*v[1] + v[2]*v[2] + v[3]*v[3];
    #pragma unroll
    for (int m = 1; m < 64; m <<= 1) s += __shfl_xor(s, m);
    if (lane == 0) { sq[r] = s; pos_sums[r] = 0.f; neg_sums[r] = 0.f; }
    __hip_bfloat16 o4[4];
    #pragma unroll
    for (int i = 0; i < 4; i++) o4[i] = __float2bfloat16(v[i]);
    {   // elems 4*lane.. -> octet o=lane>>1, pos=4*(lane&1); K/8=32
        int o = lane >> 1, pos = 4 * (lane & 1);
        size_t S = ((size_t)g * 32 + o) * 16 + rr;
        *(uint2*)&Obp[S * 8 + pos] = *(uint2*)o4;
    }

    float2 lv = ((const float2*)labels)[r * 64 + lane];
    float ls = lv.x * lv.x + lv.y * lv.y;
    #pragma unroll
    for (int m = 1; m < 64; m <<= 1) ls += __shfl_xor(ls, m);
    float nrm = sqrtf(ls) + 1e-12f;
    __hip_bfloat16 l2[2] = { __float2bfloat16(lv.x / nrm),
                             __float2bfloat16(lv.y / nrm) };
    {   // elems 2*lane.. -> octet o=lane>>2, pos=2*(lane&3); K/8=16
        int o = lane >> 2, pos = 2 * (lane & 3);
        size_t S = ((size_t)g * 16 + o) * 16 + rr;
        *(unsigned*)&Lnp[S * 8 + pos] = *(unsigned*)l2;
    }

    if (blockIdx.x == 0 && threadIdx.x == 0) {
        stats[0] = 0xFFFFFFFFu; stats[1] = 0u; stats[2] = 0u;
    }
}

// ------------------------------------ packed direct-global 64x64 gram ----
// KD8 = K/8 (16 for Ln, 32 for Ob). Fragment (mi,kc): 16-B slot
// (rb16+mi)*KD8*16 + kc*64 + lane -> one coalesced 1-KB dwordx4 per wave.
template<int KD8>
__device__ __forceinline__ void gram_packed(
    const short* __restrict__ P, int rb16, int cb16, int lane,
    f32x4 (&acc)[4][4]) {
    #pragma unroll
    for (int mi = 0; mi < 4; mi++)
        #pragma unroll
        for (int ni = 0; ni < 4; ni++) {
            f32x4 z = {0.f, 0.f, 0.f, 0.f};
            acc[mi][ni] = z;
        }
    #pragma unroll
    for (int kc = 0; kc < KD8 / 4; kc++) {
        bf16x8 a[4], b[4];
        #pragma unroll
        for (int mi = 0; mi < 4; mi++)
            a[mi] = *(const bf16x8*)&P[((size_t)(rb16 + mi) * KD8 * 16
                                        + kc * 64 + lane) * 8];
        #pragma unroll
        for (int ni = 0; ni < 4; ni++)
            b[ni] = *(const bf16x8*)&P[((size_t)(cb16 + ni) * KD8 * 16
                                        + kc * 64 + lane) * 8];
        #pragma unroll
        for (int mi = 0; mi < 4; mi++)
            #pragma unroll
            for (int ni = 0; ni < 4; ni++)
                acc[mi][ni] = __builtin_amdgcn_mfma_f32_16x16x32_bf16(
                    a[mi], b[ni], acc[mi][ni], 0, 0, 0);
    }
}

// ---------------------------------------------------------------- stats ----
__global__ __launch_bounds__(256, 3) void stats_kernel(
    const short* __restrict__ Lnp, const short* __restrict__ Obp,
    const float* __restrict__ sq, unsigned* __restrict__ stats) {
    int bi, bj;
    tri_decode_swz(blockIdx.x, bi, bj);
    int tid = threadIdx.x, lane = tid & 63, wid = tid >> 6;
    int wm = (wid >> 1) * 64, wn = (wid & 1) * 64;
    int l15 = lane & 15, quad = lane >> 4;
    int rb16 = bi * 8 + (wid >> 1) * 4, cb16 = bj * 8 + (wid & 1) * 4;
    int rB = bi * TILE, cB = bj * TILE;

    float lmin = 1e30f, lmax = -1e30f, dmax = 0.f;
    f32x4 acc[4][4];

    gram_packed<16>(Lnp, rb16, cb16, lane, acc);
    #pragma unroll
    for (int mi = 0; mi < 4; mi++)
        #pragma unroll
        for (int ni = 0; ni < 4; ni++)
            #pragma unroll
            for (int r = 0; r < 4; r++) {
                float s = acc[mi][ni][r];
                lmin = fminf(lmin, s);
                lmax = fmaxf(lmax, s);
            }

    gram_packed<32>(Obp, rb16, cb16, lane, acc);
    float sqj[4];
    #pragma unroll
    for (int ni = 0; ni < 4; ni++) sqj[ni] = sq[cB + wn + ni * 16 + l15];
    #pragma unroll
    for (int mi = 0; mi < 4; mi++) {
        f32x4 sqi = *(const f32x4*)&sq[rB + wm + mi * 16 + quad * 4];
        #pragma unroll
        for (int r = 0; r < 4; r++)
            #pragma unroll
            for (int ni = 0; ni < 4; ni++) {
                float d2 = fmaxf(sqi[r] + sqj[ni] - 2.f * acc[mi][ni][r], 0.f);
                dmax = fmaxf(dmax, d2);
            }
    }

    #pragma unroll
    for (int m = 1; m < 64; m <<= 1) {
        lmin = fminf(lmin, __shfl_xor(lmin, m));
        lmax = fmaxf(lmax, __shfl_xor(lmax, m));
        dmax = fmaxf(dmax, __shfl_xor(dmax, m));
    }
    __shared__ float red[3][4];
    if ((tid & 63) == 0) { red[0][wid] = lmin; red[1][wid] = lmax; red[2][wid] = dmax; }
    __syncthreads();
    if (tid == 0) {
        lmin = fminf(fminf(red[0][0], red[0][1]), fminf(red[0][2], red[0][3]));
        lmax = fmaxf(fmaxf(red[1][0], red[1][1]), fmaxf(red[1][2], red[1][3]));
        dmax = fmaxf(fmaxf(red[2][0], red[2][1]), fmaxf(red[2][2], red[2][3]));
        atomicMin(&stats[0], fenc(lmin));
        atomicMax(&stats[1], fenc(lmax));
        atomicMax(&stats[2], fenc(dmax));
    }
}

// ----------------------------------------------------------------- loss ----
// Dual MFMA accumulators (accS sim, accG gram) — both live in AGPRs, the
// r2-proven no-spill shape. Epilogue reads both directly.
__global__ __launch_bounds__(256, 2) void loss_kernel(
    const short* __restrict__ Lnp, const short* __restrict__ Obp,
    const float* __restrict__ sq, const unsigned* __restrict__ stats,
    float* __restrict__ pos_sums, float* __restrict__ neg_sums) {
    int bi, bj;
    tri_decode_swz(blockIdx.x, bi, bj);
    int tid = threadIdx.x, lane = tid & 63, wid = tid >> 6;
    int wm = (wid >> 1) * 64, wn = (wid & 1) * 64;
    int l15 = lane & 15, quad = lane >> 4;
    int rb16 = bi * 8 + (wid >> 1) * 4, cb16 = bj * 8 + (wid & 1) * 4;
    int rB = bi * TILE, cB = bj * TILE;

    __shared__ float rP[TILE][2], rN[TILE][2];
    __shared__ float cP[TILE][2], cN[TILE][2];

    f32x4 accS[4][4], accG[4][4];
    gram_packed<16>(Lnp, rb16, cb16, lane, accS);
    gram_packed<32>(Obp, rb16, cb16, lane, accG);

    float smin = fdec(stats[0]);
    float smax = fdec(stats[1]);
    float d2max = fdec(stats[2]);
    float invr = 1.f / (smax - smin);
    float invem = rsqrtf(d2max);

    float sqj[4];
    #pragma unroll
    for (int ni = 0; ni < 4; ni++) sqj[ni] = sq[cB + wn + ni * 16 + l15];
    float cpsum[4] = {0.f, 0.f, 0.f, 0.f};
    float cnsum[4] = {0.f, 0.f, 0.f, 0.f};

    #pragma unroll
    for (int mi = 0; mi < 4; mi++) {
        f32x4 sqi = *(const f32x4*)&sq[rB + wm + mi * 16 + quad * 4];
        float ps[4] = {0.f, 0.f, 0.f, 0.f};
        float ns[4] = {0.f, 0.f, 0.f, 0.f};
        #pragma unroll
        for (int ni = 0; ni < 4; ni++) {
            #pragma unroll
            for (int r = 0; r < 4; r++) {
                float sn = (accS[mi][ni][r] - smin) * invr;
                float g = accG[mi][ni][r];
                float d2 = fmaxf(sqi[r] + sqj[ni] - 2.f * g, 0.f);
                float eud = (d2 > 0.f) ? sqrtf(d2) * invem : 0.f;
                float dist = eud + sn;
                bool pos = sn > 0.5f;   // TAU
                float pv = pos ? __expf(dist) : 0.f;
                float nv = pos ? 0.f : __expf(1.0f - dist);  // MAG = 1
                ps[r] += pv;  ns[r] += nv;
                cpsum[ni] += pv;  cnsum[ni] += nv;
            }
        }
        #pragma unroll
        for (int r = 0; r < 4; r++) {
            #pragma unroll
            for (int m = 1; m < 16; m <<= 1) {
                ps[r] += __shfl_xor(ps[r], m);
                ns[r] += __shfl_xor(ns[r], m);
            }
            if (l15 == 0) {
                int rr = wm + mi * 16 + quad * 4 + r;
                rP[rr][wid & 1] = ps[r];
                rN[rr][wid & 1] = ns[r];
            }
        }
    }
    #pragma unroll
    for (int ni = 0; ni < 4; ni++) {
        #pragma unroll
        for (int m = 16; m < 64; m <<= 1) {
            cpsum[ni] += __shfl_xor(cpsum[ni], m);
            cnsum[ni] += __shfl_xor(cnsum[ni], m);
        }
        if (quad == 0) {
            int cc = wn + ni * 16 + l15;
            cP[cc][wid >> 1] = cpsum[ni];
            cN[cc][wid >> 1] = cnsum[ni];
        }
    }
    __syncthreads();
    if (tid < TILE) {
        atomicAdd(&pos_sums[bi * TILE + tid], rP[tid][0] + rP[tid][1]);
        atomicAdd(&neg_sums[bi * TILE + tid], rN[tid][0] + rN[tid][1]);
        if (bi != bj) {
            atomicAdd(&pos_sums[bj * TILE + tid], cP[tid][0] + cP[tid][1]);
            atomicAdd(&neg_sums[bj * TILE + tid], cN[tid][0] + cN[tid][1]);
        }
    }
}

// ------------------------------------------------------------- finalize ----
__global__ __launch_bounds__(256) void finalize_kernel(
    const float* __restrict__ pos_sums, const float* __restrict__ neg_sums,
    float* __restrict__ out) {
    int t = threadIdx.x;
    float acc = 0.f;
    for (int i = t; i < B_N; i += 256) {
        float p = pos_sums[i], n = neg_sums[i];
        float pl = fmaxf(logf(p), 0.f);
        float nl = (n > 0.f) ? fmaxf(logf(n), 0.f) : 0.f;
        acc += pl + nl;
    }
    #pragma unroll
    for (int m = 1; m < 64; m <<= 1) acc += __shfl_xor(acc, m);
    __shared__ float w4[4];
    if ((t & 63) == 0) w4[t >> 6] = acc;
    __syncthreads();
    if (t == 0) out[0] = (w4[0] + w4[1] + w4[2] + w4[3]) / (float)B_N;
}

// ------------------------------------------------------------------ entry ----
extern "C" void kernel_launch(void* const* d_in, const int* in_sizes, int n_in,
                              void* d_out, int out_size, void* d_ws, size_t ws_size,
                              hipStream_t stream) {
    const float* outputs = (const float*)d_in[0];
    const float* labels  = (const float*)d_in[1];
    float* out = (float*)d_out;
    char* ws = (char*)d_ws;
    __hip_bfloat16* Obp = (__hip_bfloat16*)(ws);
    __hip_bfloat16* Lnp = (__hip_bfloat16*)(ws + 4194304);
    float* sq           = (float*)(ws + 6291456);
    float* pos_sums     = (float*)(ws + 6324224);
    float* neg_sums     = (float*)(ws + 6356992);
    unsigned* stats     = (unsigned*)(ws + 6389760);

    prep_kernel<<<B_N / 4, 256, 0, stream>>>(outputs, labels, Obp, Lnp, sq,
                                             pos_sums, neg_sums, stats);
    stats_kernel<<<NTRI, 256, 0, stream>>>((const short*)Lnp, (const short*)Obp,
                                           sq, stats);
    loss_kernel<<<NTRI, 256, 0, stream>>>((const short*)Lnp, (const short*)Obp,
                                          sq, stats, pos_sums, neg_sums);
    finalize_kernel<<<1, 256, 0, stream>>>(pos_sums, neg_sums, out);
}

// Round 14
// 249.490 us; speedup vs baseline: 1.0080x; 1.0080x over previous
//
#include <hip/hip_runtime.h>
#include <hip/hip_bf16.h>

// WeightedLoss round 14: supertile block ordering + coalesced prep.
// r13 disproved the spill theory (WRITE_SIZE byte-identical with/without the
// sim cache): the 64 MB write + 99 MB fetch is L2-boundary traffic — B-tile
// fragments thrash the 4 MB per-XCD L2 because bj spans all 64 tile-columns.
// Fix 1: enumerate tiles in 16x16-tile supertiles (diag-tri 136 + offdiag 256
// blocks) so any ~512-block concurrent window touches ~3 MB -> L2-resident.
// Fix 2: prep writes the packed layout via LDS transpose in contiguous 8/4 KB
// group blocks (old prep scattered 16 B per 256-B stride -> partial lines).
// ws: [0] Obp bf16 packed 4 MB | [4194304] Lnp bf16 packed 2 MB
//     [6291456] sq f32 | [6324224] pos_sums | [6356992] neg_sums
//     [6389760] stats u32[3]

#define B_N 8192
#define NT   64
#define TILE 128
#define NTRI 2080

typedef __attribute__((ext_vector_type(8))) short bf16x8;
typedef __attribute__((ext_vector_type(4))) float f32x4;

__device__ __forceinline__ unsigned fenc(float f) {
    unsigned u = __float_as_uint(f);
    return (u & 0x80000000u) ? ~u : (u | 0x80000000u);
}
__device__ __forceinline__ float fdec(unsigned k) {
    unsigned u = (k & 0x80000000u) ? (k ^ 0x80000000u) : ~k;
    return __uint_as_float(u);
}

// Supertile decode: 4 diagonal 16x16-tri supertiles (136 tiles each, b<544),
// then 6 off-diagonal 16x16 supertiles (256 tiles each). bi<=bj always.
__device__ __forceinline__ void tile_decode(int b, int& bi, int& bj) {
    int si, sj, ti, tj;
    if (b < 544) {
        int sb = b / 136, w = b - sb * 136;
        int i = 0;
        while (w >= 16 - i) { w -= 16 - i; i++; }
        si = sb; sj = sb; ti = i; tj = i + w;
    } else {
        int q = (b - 544) >> 8, w = (b - 544) & 255;
        int i = 0;
        while (q >= 3 - i) { q -= 3 - i; i++; }
        si = i; sj = i + 1 + q;
        ti = w >> 4; tj = w & 15;
    }
    bi = si * 16 + ti; bj = sj * 16 + tj;
}

// ---------------------------------------------------------------- prep ----
// One block per 16-row group g. LDS transpose -> contiguous packed writes:
// Obp group block = 8 KB at elem g*4096, Lnp = 4 KB at elem g*2048.
__global__ __launch_bounds__(256) void prep_kernel(
    const float* __restrict__ outputs, const float* __restrict__ labels,
    __hip_bfloat16* __restrict__ Obp, __hip_bfloat16* __restrict__ Lnp,
    float* __restrict__ sq, float* __restrict__ pos_sums,
    float* __restrict__ neg_sums, unsigned* __restrict__ stats) {
    int g = blockIdx.x, tid = threadIdx.x;
    int rl = tid >> 4, c = tid & 15;       // row-local 0..15, col-chunk 0..15
    int row = g * 16 + rl;
    __shared__ __align__(16) short tO[16][264];   // 16x256 bf16, +8 pad
    __shared__ __align__(16) short tL[16][136];   // 16x128 bf16, +8 pad

    // outputs row: 16 f32 per thread
    float s = 0.f;
    #pragma unroll
    for (int k = 0; k < 4; k++) {
        f32x4 v = *(const f32x4*)&outputs[(size_t)row * 256 + c * 16 + k * 4];
        s += v[0]*v[0] + v[1]*v[1] + v[2]*v[2] + v[3]*v[3];
        __hip_bfloat16 b4[4];
        #pragma unroll
        for (int i = 0; i < 4; i++) b4[i] = __float2bfloat16(v[i]);
        *(uint2*)&tO[rl][c * 16 + k * 4] = *(uint2*)b4;
    }
    #pragma unroll
    for (int m = 1; m < 16; m <<= 1) s += __shfl_xor(s, m);
    if (c == 0) sq[row] = s;

    // labels row: 8 f32 per thread
    float ls = 0.f;
    f32x4 u0 = *(const f32x4*)&labels[(size_t)row * 128 + c * 8];
    f32x4 u1 = *(const f32x4*)&labels[(size_t)row * 128 + c * 8 + 4];
    ls += u0[0]*u0[0] + u0[1]*u0[1] + u0[2]*u0[2] + u0[3]*u0[3];
    ls += u1[0]*u1[0] + u1[1]*u1[1] + u1[2]*u1[2] + u1[3]*u1[3];
    #pragma unroll
    for (int m = 1; m < 16; m <<= 1) ls += __shfl_xor(ls, m);
    float inv = 1.f / (sqrtf(ls) + 1e-12f);
    {
        __hip_bfloat16 b4[4];
        #pragma unroll
        for (int i = 0; i < 4; i++) b4[i] = __float2bfloat16(u0[i] * inv);
        *(uint2*)&tL[rl][c * 8] = *(uint2*)b4;
        #pragma unroll
        for (int i = 0; i < 4; i++) b4[i] = __float2bfloat16(u1[i] * inv);
        *(uint2*)&tL[rl][c * 8 + 4] = *(uint2*)b4;
    }
    if (tid < 16) { pos_sums[g * 16 + tid] = 0.f; neg_sums[g * 16 + tid] = 0.f; }
    if (g == 0 && tid == 0) {
        stats[0] = 0xFFFFFFFFu; stats[1] = 0u; stats[2] = 0u;
    }
    __syncthreads();

    // Obp: thread t writes slots 2t, 2t+1 (32 B contiguous)
    #pragma unroll
    for (int q = 0; q < 2; q++) {
        int sl = tid * 2 + q;
        int o = sl >> 4, rr = sl & 15;
        uint4 d = *(uint4*)&tO[rr][o * 8];
        *(uint4*)&Obp[(size_t)g * 4096 + (size_t)sl * 8] = d;
    }
    // Lnp: thread t writes slot t (16 B)
    {
        int o = tid >> 4, rr = tid & 15;
        uint4 d = *(uint4*)&tL[rr][o * 8];
        *(uint4*)&Lnp[(size_t)g * 2048 + (size_t)tid * 8] = d;
    }
}

// ------------------------------------ packed direct-global 64x64 gram ----
// KD8 = K/8 (16 for Ln, 32 for Ob). Fragment (mi,kc): 16-B slot
// (rb16+mi)*KD8*16 + kc*64 + lane -> one coalesced 1-KB dwordx4 per wave.
template<int KD8>
__device__ __forceinline__ void gram_packed(
    const short* __restrict__ P, int rb16, int cb16, int lane,
    f32x4 (&acc)[4][4]) {
    #pragma unroll
    for (int mi = 0; mi < 4; mi++)
        #pragma unroll
        for (int ni = 0; ni < 4; ni++) {
            f32x4 z = {0.f, 0.f, 0.f, 0.f};
            acc[mi][ni] = z;
        }
    #pragma unroll
    for (int kc = 0; kc < KD8 / 4; kc++) {
        bf16x8 a[4], b[4];
        #pragma unroll
        for (int mi = 0; mi < 4; mi++)
            a[mi] = *(const bf16x8*)&P[((size_t)(rb16 + mi) * KD8 * 16
                                        + kc * 64 + lane) * 8];
        #pragma unroll
        for (int ni = 0; ni < 4; ni++)
            b[ni] = *(const bf16x8*)&P[((size_t)(cb16 + ni) * KD8 * 16
                                        + kc * 64 + lane) * 8];
        #pragma unroll
        for (int mi = 0; mi < 4; mi++)
            #pragma unroll
            for (int ni = 0; ni < 4; ni++)
                acc[mi][ni] = __builtin_amdgcn_mfma_f32_16x16x32_bf16(
                    a[mi], b[ni], acc[mi][ni], 0, 0, 0);
    }
}

// ---------------------------------------------------------------- stats ----
__global__ __launch_bounds__(256, 3) void stats_kernel(
    const short* __restrict__ Lnp, const short* __restrict__ Obp,
    const float* __restrict__ sq, unsigned* __restrict__ stats) {
    int bi, bj;
    tile_decode(blockIdx.x, bi, bj);
    int tid = threadIdx.x, lane = tid & 63, wid = tid >> 6;
    int wm = (wid >> 1) * 64, wn = (wid & 1) * 64;
    int l15 = lane & 15, quad = lane >> 4;
    int rb16 = bi * 8 + (wid >> 1) * 4, cb16 = bj * 8 + (wid & 1) * 4;
    int rB = bi * TILE, cB = bj * TILE;

    float lmin = 1e30f, lmax = -1e30f, dmax = 0.f;
    f32x4 acc[4][4];

    gram_packed<16>(Lnp, rb16, cb16, lane, acc);
    #pragma unroll
    for (int mi = 0; mi < 4; mi++)
        #pragma unroll
        for (int ni = 0; ni < 4; ni++)
            #pragma unroll
            for (int r = 0; r < 4; r++) {
                float s = acc[mi][ni][r];
                lmin = fminf(lmin, s);
                lmax = fmaxf(lmax, s);
            }

    gram_packed<32>(Obp, rb16, cb16, lane, acc);
    float sqj[4];
    #pragma unroll
    for (int ni = 0; ni < 4; ni++) sqj[ni] = sq[cB + wn + ni * 16 + l15];
    #pragma unroll
    for (int mi = 0; mi < 4; mi++) {
        f32x4 sqi = *(const f32x4*)&sq[rB + wm + mi * 16 + quad * 4];
        #pragma unroll
        for (int r = 0; r < 4; r++)
            #pragma unroll
            for (int ni = 0; ni < 4; ni++) {
                float d2 = fmaxf(sqi[r] + sqj[ni] - 2.f * acc[mi][ni][r], 0.f);
                dmax = fmaxf(dmax, d2);
            }
    }

    #pragma unroll
    for (int m = 1; m < 64; m <<= 1) {
        lmin = fminf(lmin, __shfl_xor(lmin, m));
        lmax = fmaxf(lmax, __shfl_xor(lmax, m));
        dmax = fmaxf(dmax, __shfl_xor(dmax, m));
    }
    __shared__ float red[3][4];
    if ((tid & 63) == 0) { red[0][wid] = lmin; red[1][wid] = lmax; red[2][wid] = dmax; }
    __syncthreads();
    if (tid == 0) {
        lmin = fminf(fminf(red[0][0], red[0][1]), fminf(red[0][2], red[0][3]));
        lmax = fmaxf(fmaxf(red[1][0], red[1][1]), fmaxf(red[1][2], red[1][3]));
        dmax = fmaxf(fmaxf(red[2][0], red[2][1]), fmaxf(red[2][2], red[2][3]));
        atomicMin(&stats[0], fenc(lmin));
        atomicMax(&stats[1], fenc(lmax));
        atomicMax(&stats[2], fenc(dmax));
    }
}

// ----------------------------------------------------------------- loss ----
// Dual MFMA accumulators (accS sim, accG gram); epilogue reads both directly.
__global__ __launch_bounds__(256, 3) void loss_kernel(
    const short* __restrict__ Lnp, const short* __restrict__ Obp,
    const float* __restrict__ sq, const unsigned* __restrict__ stats,
    float* __restrict__ pos_sums, float* __restrict__ neg_sums) {
    int bi, bj;
    tile_decode(blockIdx.x, bi, bj);
    int tid = threadIdx.x, lane = tid & 63, wid = tid >> 6;
    int wm = (wid >> 1) * 64, wn = (wid & 1) * 64;
    int l15 = lane & 15, quad = lane >> 4;
    int rb16 = bi * 8 + (wid >> 1) * 4, cb16 = bj * 8 + (wid & 1) * 4;
    int rB = bi * TILE, cB = bj * TILE;

    __shared__ float rP[TILE][2], rN[TILE][2];
    __shared__ float cP[TILE][2], cN[TILE][2];

    f32x4 accS[4][4], accG[4][4];
    gram_packed<16>(Lnp, rb16, cb16, lane, accS);
    gram_packed<32>(Obp, rb16, cb16, lane, accG);

    float smin = fdec(stats[0]);
    float smax = fdec(stats[1]);
    float d2max = fdec(stats[2]);
    float invr = 1.f / (smax - smin);
    float invem = rsqrtf(d2max);

    float sqj[4];
    #pragma unroll
    for (int ni = 0; ni < 4; ni++) sqj[ni] = sq[cB + wn + ni * 16 + l15];
    float cpsum[4] = {0.f, 0.f, 0.f, 0.f};
    float cnsum[4] = {0.f, 0.f, 0.f, 0.f};

    #pragma unroll
    for (int mi = 0; mi < 4; mi++) {
        f32x4 sqi = *(const f32x4*)&sq[rB + wm + mi * 16 + quad * 4];
        float ps[4] = {0.f, 0.f, 0.f, 0.f};
        float ns[4] = {0.f, 0.f, 0.f, 0.f};
        #pragma unroll
        for (int ni = 0; ni < 4; ni++) {
            #pragma unroll
            for (int r = 0; r < 4; r++) {
                float sn = (accS[mi][ni][r] - smin) * invr;
                float g = accG[mi][ni][r];
                float d2 = fmaxf(sqi[r] + sqj[ni] - 2.f * g, 0.f);
                float eud = (d2 > 0.f) ? sqrtf(d2) * invem : 0.f;
                float dist = eud + sn;
                bool pos = sn > 0.5f;   // TAU
                float pv = pos ? __expf(dist) : 0.f;
                float nv = pos ? 0.f : __expf(1.0f - dist);  // MAG = 1
                ps[r] += pv;  ns[r] += nv;
                cpsum[ni] += pv;  cnsum[ni] += nv;
            }
        }
        #pragma unroll
        for (int r = 0; r < 4; r++) {
            #pragma unroll
            for (int m = 1; m < 16; m <<= 1) {
                ps[r] += __shfl_xor(ps[r], m);
                ns[r] += __shfl_xor(ns[r], m);
            }
            if (l15 == 0) {
                int rr = wm + mi * 16 + quad * 4 + r;
                rP[rr][wid & 1] = ps[r];
                rN[rr][wid & 1] = ns[r];
            }
        }
    }
    #pragma unroll
    for (int ni = 0; ni < 4; ni++) {
        #pragma unroll
        for (int m = 16; m < 64; m <<= 1) {
            cpsum[ni] += __shfl_xor(cpsum[ni], m);
            cnsum[ni] += __shfl_xor(cnsum[ni], m);
        }
        if (quad == 0) {
            int cc = wn + ni * 16 + l15;
            cP[cc][wid >> 1] = cpsum[ni];
            cN[cc][wid >> 1] = cnsum[ni];
        }
    }
    __syncthreads();
    if (tid < TILE) {
        atomicAdd(&pos_sums[bi * TILE + tid], rP[tid][0] + rP[tid][1]);
        atomicAdd(&neg_sums[bi * TILE + tid], rN[tid][0] + rN[tid][1]);
        if (bi != bj) {
            atomicAdd(&pos_sums[bj * TILE + tid], cP[tid][0] + cP[tid][1]);
            atomicAdd(&neg_sums[bj * TILE + tid], cN[tid][0] + cN[tid][1]);
        }
    }
}

// ------------------------------------------------------------- finalize ----
__global__ __launch_bounds__(256) void finalize_kernel(
    const float* __restrict__ pos_sums, const float* __restrict__ neg_sums,
    float* __restrict__ out) {
    int t = threadIdx.x;
    float acc = 0.f;
    for (int i = t; i < B_N; i += 256) {
        float p = pos_sums[i], n = neg_sums[i];
        float pl = fmaxf(logf(p), 0.f);
        float nl = (n > 0.f) ? fmaxf(logf(n), 0.f) : 0.f;
        acc += pl + nl;
    }
    #pragma unroll
    for (int m = 1; m < 64; m <<= 1) acc += __shfl_xor(acc, m);
    __shared__ float w4[4];
    if ((t & 63) == 0) w4[t >> 6] = acc;
    __syncthreads();
    if (t == 0) out[0] = (w4[0] + w4[1] + w4[2] + w4[3]) / (float)B_N;
}

// ------------------------------------------------------------------ entry ----
extern "C" void kernel_launch(void* const* d_in, const int* in_sizes, int n_in,
                              void* d_out, int out_size, void* d_ws, size_t ws_size,
                              hipStream_t stream) {
    const float* outputs = (const float*)d_in[0];
    const float* labels  = (const float*)d_in[1];
    float* out = (float*)d_out;
    char* ws = (char*)d_ws;
    __hip_bfloat16* Obp = (__hip_bfloat16*)(ws);
    __hip_bfloat16* Lnp = (__hip_bfloat16*)(ws + 4194304);
    float* sq           = (float*)(ws + 6291456);
    float* pos_sums     = (float*)(ws + 6324224);
    float* neg_sums     = (float*)(ws + 6356992);
    unsigned* stats     = (unsigned*)(ws + 6389760);

    prep_kernel<<<B_N / 16, 256, 0, stream>>>(outputs, labels, Obp, Lnp, sq,
                                              pos_sums, neg_sums, stats);
    stats_kernel<<<NTRI, 256, 0, stream>>>((const short*)Lnp, (const short*)Obp,
                                           sq, stats);
    loss_kernel<<<NTRI, 256, 0, stream>>>((const short*)Lnp, (const short*)Obp,
                                          sq, stats, pos_sums, neg_sums);
    finalize_kernel<<<1, 256, 0, stream>>>(pos_sums, neg_sums, out);
}

// Round 15
// 222.430 us; speedup vs baseline: 1.1306x; 1.1217x over previous
//
#include <hip/hip_runtime.h>
#include <hip/hip_bf16.h>

// WeightedLoss round 15: per-thread-private LDS sim park — structurally
// spill-proof loss. r13/r14 proved the persistent 54-64 MB WRITE_SIZE is
// deterministic per-thread scratch (26-30 dwords/thread): peak liveness of
// accS+accG (128 AGPRs) + the packed gram's hoisted load pipeline exceeds
// the register budget regardless of how the sim cache is declared. Fix:
// after gram S each lane packs its 32 sim values into a PRIVATE 72-B LDS
// slot (stride 18 dwords -> free 2-way banking, no barrier: same-thread
// read-back), so accS dies before gram G -> peak ~140 regs, no spill,
// 3 waves/SIMD. Packed fragments + supertile ordering + coalesced prep kept.
// ws: [0] Obp bf16 packed 4 MB | [4194304] Lnp bf16 packed 2 MB
//     [6291456] sq f32 | [6324224] pos_sums | [6356992] neg_sums
//     [6389760] stats u32[3]

#define B_N 8192
#define NT   64
#define TILE 128
#define NTRI 2080

typedef __attribute__((ext_vector_type(8))) short bf16x8;
typedef __attribute__((ext_vector_type(4))) float f32x4;
typedef __attribute__((ext_vector_type(2))) _Float16 f16x2;

__device__ __forceinline__ unsigned fenc(float f) {
    unsigned u = __float_as_uint(f);
    return (u & 0x80000000u) ? ~u : (u | 0x80000000u);
}
__device__ __forceinline__ float fdec(unsigned k) {
    unsigned u = (k & 0x80000000u) ? (k ^ 0x80000000u) : ~k;
    return __uint_as_float(u);
}
__device__ __forceinline__ unsigned pack2(float a, float b) {
    f16x2 p; p[0] = (_Float16)a; p[1] = (_Float16)b;
    return *(unsigned*)&p;
}

// Supertile decode: 4 diagonal 16x16-tri supertiles (136 tiles each, b<544),
// then 6 off-diagonal 16x16 supertiles (256 tiles each). bi<=bj always.
__device__ __forceinline__ void tile_decode(int b, int& bi, int& bj) {
    int si, sj, ti, tj;
    if (b < 544) {
        int sb = b / 136, w = b - sb * 136;
        int i = 0;
        while (w >= 16 - i) { w -= 16 - i; i++; }
        si = sb; sj = sb; ti = i; tj = i + w;
    } else {
        int q = (b - 544) >> 8, w = (b - 544) & 255;
        int i = 0;
        while (q >= 3 - i) { q -= 3 - i; i++; }
        si = i; sj = i + 1 + q;
        ti = w >> 4; tj = w & 15;
    }
    bi = si * 16 + ti; bj = sj * 16 + tj;
}

// ---------------------------------------------------------------- prep ----
// One block per 16-row group g. LDS transpose -> contiguous packed writes.
__global__ __launch_bounds__(256) void prep_kernel(
    const float* __restrict__ outputs, const float* __restrict__ labels,
    __hip_bfloat16* __restrict__ Obp, __hip_bfloat16* __restrict__ Lnp,
    float* __restrict__ sq, float* __restrict__ pos_sums,
    float* __restrict__ neg_sums, unsigned* __restrict__ stats) {
    int g = blockIdx.x, tid = threadIdx.x;
    int rl = tid >> 4, c = tid & 15;
    int row = g * 16 + rl;
    __shared__ __align__(16) short tO[16][264];
    __shared__ __align__(16) short tL[16][136];

    float s = 0.f;
    #pragma unroll
    for (int k = 0; k < 4; k++) {
        f32x4 v = *(const f32x4*)&outputs[(size_t)row * 256 + c * 16 + k * 4];
        s += v[0]*v[0] + v[1]*v[1] + v[2]*v[2] + v[3]*v[3];
        __hip_bfloat16 b4[4];
        #pragma unroll
        for (int i = 0; i < 4; i++) b4[i] = __float2bfloat16(v[i]);
        *(uint2*)&tO[rl][c * 16 + k * 4] = *(uint2*)b4;
    }
    #pragma unroll
    for (int m = 1; m < 16; m <<= 1) s += __shfl_xor(s, m);
    if (c == 0) sq[row] = s;

    float ls = 0.f;
    f32x4 u0 = *(const f32x4*)&labels[(size_t)row * 128 + c * 8];
    f32x4 u1 = *(const f32x4*)&labels[(size_t)row * 128 + c * 8 + 4];
    ls += u0[0]*u0[0] + u0[1]*u0[1] + u0[2]*u0[2] + u0[3]*u0[3];
    ls += u1[0]*u1[0] + u1[1]*u1[1] + u1[2]*u1[2] + u1[3]*u1[3];
    #pragma unroll
    for (int m = 1; m < 16; m <<= 1) ls += __shfl_xor(ls, m);
    float inv = 1.f / (sqrtf(ls) + 1e-12f);
    {
        __hip_bfloat16 b4[4];
        #pragma unroll
        for (int i = 0; i < 4; i++) b4[i] = __float2bfloat16(u0[i] * inv);
        *(uint2*)&tL[rl][c * 8] = *(uint2*)b4;
        #pragma unroll
        for (int i = 0; i < 4; i++) b4[i] = __float2bfloat16(u1[i] * inv);
        *(uint2*)&tL[rl][c * 8 + 4] = *(uint2*)b4;
    }
    if (tid < 16) { pos_sums[g * 16 + tid] = 0.f; neg_sums[g * 16 + tid] = 0.f; }
    if (g == 0 && tid == 0) {
        stats[0] = 0xFFFFFFFFu; stats[1] = 0u; stats[2] = 0u;
    }
    __syncthreads();

    #pragma unroll
    for (int q = 0; q < 2; q++) {
        int sl = tid * 2 + q;
        int o = sl >> 4, rr = sl & 15;
        uint4 d = *(uint4*)&tO[rr][o * 8];
        *(uint4*)&Obp[(size_t)g * 4096 + (size_t)sl * 8] = d;
    }
    {
        int o = tid >> 4, rr = tid & 15;
        uint4 d = *(uint4*)&tL[rr][o * 8];
        *(uint4*)&Lnp[(size_t)g * 2048 + (size_t)tid * 8] = d;
    }
}

// ------------------------------------ packed direct-global 64x64 gram ----
template<int KD8>
__device__ __forceinline__ void gram_packed(
    const short* __restrict__ P, int rb16, int cb16, int lane,
    f32x4 (&acc)[4][4]) {
    #pragma unroll
    for (int mi = 0; mi < 4; mi++)
        #pragma unroll
        for (int ni = 0; ni < 4; ni++) {
            f32x4 z = {0.f, 0.f, 0.f, 0.f};
            acc[mi][ni] = z;
        }
    #pragma unroll
    for (int kc = 0; kc < KD8 / 4; kc++) {
        bf16x8 a[4], b[4];
        #pragma unroll
        for (int mi = 0; mi < 4; mi++)
            a[mi] = *(const bf16x8*)&P[((size_t)(rb16 + mi) * KD8 * 16
                                        + kc * 64 + lane) * 8];
        #pragma unroll
        for (int ni = 0; ni < 4; ni++)
            b[ni] = *(const bf16x8*)&P[((size_t)(cb16 + ni) * KD8 * 16
                                        + kc * 64 + lane) * 8];
        #pragma unroll
        for (int mi = 0; mi < 4; mi++)
            #pragma unroll
            for (int ni = 0; ni < 4; ni++)
                acc[mi][ni] = __builtin_amdgcn_mfma_f32_16x16x32_bf16(
                    a[mi], b[ni], acc[mi][ni], 0, 0, 0);
    }
}

// ---------------------------------------------------------------- stats ----
__global__ __launch_bounds__(256, 3) void stats_kernel(
    const short* __restrict__ Lnp, const short* __restrict__ Obp,
    const float* __restrict__ sq, unsigned* __restrict__ stats) {
    int bi, bj;
    tile_decode(blockIdx.x, bi, bj);
    int tid = threadIdx.x, lane = tid & 63, wid = tid >> 6;
    int wm = (wid >> 1) * 64, wn = (wid & 1) * 64;
    int l15 = lane & 15, quad = lane >> 4;
    int rb16 = bi * 8 + (wid >> 1) * 4, cb16 = bj * 8 + (wid & 1) * 4;
    int rB = bi * TILE, cB = bj * TILE;

    float lmin = 1e30f, lmax = -1e30f, dmax = 0.f;
    f32x4 acc[4][4];

    gram_packed<16>(Lnp, rb16, cb16, lane, acc);
    #pragma unroll
    for (int mi = 0; mi < 4; mi++)
        #pragma unroll
        for (int ni = 0; ni < 4; ni++)
            #pragma unroll
            for (int r = 0; r < 4; r++) {
                float s = acc[mi][ni][r];
                lmin = fminf(lmin, s);
                lmax = fmaxf(lmax, s);
            }

    gram_packed<32>(Obp, rb16, cb16, lane, acc);
    float sqj[4];
    #pragma unroll
    for (int ni = 0; ni < 4; ni++) sqj[ni] = sq[cB + wn + ni * 16 + l15];
    #pragma unroll
    for (int mi = 0; mi < 4; mi++) {
        f32x4 sqi = *(const f32x4*)&sq[rB + wm + mi * 16 + quad * 4];
        #pragma unroll
        for (int r = 0; r < 4; r++)
            #pragma unroll
            for (int ni = 0; ni < 4; ni++) {
                float d2 = fmaxf(sqi[r] + sqj[ni] - 2.f * acc[mi][ni][r], 0.f);
                dmax = fmaxf(dmax, d2);
            }
    }

    #pragma unroll
    for (int m = 1; m < 64; m <<= 1) {
        lmin = fminf(lmin, __shfl_xor(lmin, m));
        lmax = fmaxf(lmax, __shfl_xor(lmax, m));
        dmax = fmaxf(dmax, __shfl_xor(dmax, m));
    }
    __shared__ float red[3][4];
    if ((tid & 63) == 0) { red[0][wid] = lmin; red[1][wid] = lmax; red[2][wid] = dmax; }
    __syncthreads();
    if (tid == 0) {
        lmin = fminf(fminf(red[0][0], red[0][1]), fminf(red[0][2], red[0][3]));
        lmax = fmaxf(fmaxf(red[1][0], red[1][1]), fmaxf(red[1][2], red[1][3]));
        dmax = fmaxf(fmaxf(red[2][0], red[2][1]), fmaxf(red[2][2], red[2][3]));
        atomicMin(&stats[0], fenc(lmin));
        atomicMax(&stats[1], fenc(lmax));
        atomicMax(&stats[2], fenc(dmax));
    }
}

// ----------------------------------------------------------------- loss ----
// gram S -> pack raw sim into PRIVATE LDS slot (72 B/thread, no barrier,
// free 2-way banking) -> gram G into the SAME acc regs -> epilogue reads
// the parked sim back. accS never coexists with accG: no spill.
__global__ __launch_bounds__(256, 3) void loss_kernel(
    const short* __restrict__ Lnp, const short* __restrict__ Obp,
    const float* __restrict__ sq, const unsigned* __restrict__ stats,
    float* __restrict__ pos_sums, float* __restrict__ neg_sums) {
    int bi, bj;
    tile_decode(blockIdx.x, bi, bj);
    int tid = threadIdx.x, lane = tid & 63, wid = tid >> 6;
    int wm = (wid >> 1) * 64, wn = (wid & 1) * 64;
    int l15 = lane & 15, quad = lane >> 4;
    int rb16 = bi * 8 + (wid >> 1) * 4, cb16 = bj * 8 + (wid & 1) * 4;
    int rB = bi * TILE, cB = bj * TILE;

    __shared__ unsigned simW[256 * 18];   // 18 KB: 72 B per thread (16 used)
    __shared__ float rP[TILE][2], rN[TILE][2];
    __shared__ float cP[TILE][2], cN[TILE][2];
    unsigned* my = &simW[tid * 18];

    f32x4 acc[4][4];

    // --- sim gram; park raw sim in private LDS slot ---
    gram_packed<16>(Lnp, rb16, cb16, lane, acc);
    #pragma unroll
    for (int mi = 0; mi < 4; mi++)
        #pragma unroll
        for (int ni = 0; ni < 4; ni++) {
            my[(mi * 4 + ni) * 2 + 0] = pack2(acc[mi][ni][0], acc[mi][ni][1]);
            my[(mi * 4 + ni) * 2 + 1] = pack2(acc[mi][ni][2], acc[mi][ni][3]);
        }

    // --- outputs gram (same acc registers) ---
    gram_packed<32>(Obp, rb16, cb16, lane, acc);

    float smin = fdec(stats[0]);
    float smax = fdec(stats[1]);
    float d2max = fdec(stats[2]);
    float invr = 1.f / (smax - smin);
    float invem = rsqrtf(d2max);

    float sqj[4];
    #pragma unroll
    for (int ni = 0; ni < 4; ni++) sqj[ni] = sq[cB + wn + ni * 16 + l15];
    float cpsum[4] = {0.f, 0.f, 0.f, 0.f};
    float cnsum[4] = {0.f, 0.f, 0.f, 0.f};

    #pragma unroll
    for (int mi = 0; mi < 4; mi++) {
        f32x4 sqi = *(const f32x4*)&sq[rB + wm + mi * 16 + quad * 4];
        float ps[4] = {0.f, 0.f, 0.f, 0.f};
        float ns[4] = {0.f, 0.f, 0.f, 0.f};
        #pragma unroll
        for (int ni = 0; ni < 4; ni++) {
            f16x2 s01 = ((const f16x2*)my)[(mi * 4 + ni) * 2 + 0];
            f16x2 s23 = ((const f16x2*)my)[(mi * 4 + ni) * 2 + 1];
            #pragma unroll
            for (int r = 0; r < 4; r++) {
                float sraw = (r < 2) ? (float)s01[r] : (float)s23[r - 2];
                float sn = (sraw - smin) * invr;
                float g = acc[mi][ni][r];
                float d2 = fmaxf(sqi[r] + sqj[ni] - 2.f * g, 0.f);
                float eud = (d2 > 0.f) ? sqrtf(d2) * invem : 0.f;
                float dist = eud + sn;
                bool pos = sn > 0.5f;   // TAU
                float pv = pos ? __expf(dist) : 0.f;
                float nv = pos ? 0.f : __expf(1.0f - dist);  // MAG = 1
                ps[r] += pv;  ns[r] += nv;
                cpsum[ni] += pv;  cnsum[ni] += nv;
            }
        }
        #pragma unroll
        for (int r = 0; r < 4; r++) {
            #pragma unroll
            for (int m = 1; m < 16; m <<= 1) {
                ps[r] += __shfl_xor(ps[r], m);
                ns[r] += __shfl_xor(ns[r], m);
            }
            if (l15 == 0) {
                int rr = wm + mi * 16 + quad * 4 + r;
                rP[rr][wid & 1] = ps[r];
                rN[rr][wid & 1] = ns[r];
            }
        }
    }
    #pragma unroll
    for (int ni = 0; ni < 4; ni++) {
        #pragma unroll
        for (int m = 16; m < 64; m <<= 1) {
            cpsum[ni] += __shfl_xor(cpsum[ni], m);
            cnsum[ni] += __shfl_xor(cnsum[ni], m);
        }
        if (quad == 0) {
            int cc = wn + ni * 16 + l15;
            cP[cc][wid >> 1] = cpsum[ni];
            cN[cc][wid >> 1] = cnsum[ni];
        }
    }
    __syncthreads();
    if (tid < TILE) {
        atomicAdd(&pos_sums[bi * TILE + tid], rP[tid][0] + rP[tid][1]);
        atomicAdd(&neg_sums[bi * TILE + tid], rN[tid][0] + rN[tid][1]);
        if (bi != bj) {
            atomicAdd(&pos_sums[bj * TILE + tid], cP[tid][0] + cP[tid][1]);
            atomicAdd(&neg_sums[bj * TILE + tid], cN[tid][0] + cN[tid][1]);
        }
    }
}

// ------------------------------------------------------------- finalize ----
__global__ __launch_bounds__(256) void finalize_kernel(
    const float* __restrict__ pos_sums, const float* __restrict__ neg_sums,
    float* __restrict__ out) {
    int t = threadIdx.x;
    float acc = 0.f;
    for (int i = t; i < B_N; i += 256) {
        float p = pos_sums[i], n = neg_sums[i];
        float pl = fmaxf(logf(p), 0.f);
        float nl = (n > 0.f) ? fmaxf(logf(n), 0.f) : 0.f;
        acc += pl + nl;
    }
    #pragma unroll
    for (int m = 1; m < 64; m <<= 1) acc += __shfl_xor(acc, m);
    __shared__ float w4[4];
    if ((t & 63) == 0) w4[t >> 6] = acc;
    __syncthreads();
    if (t == 0) out[0] = (w4[0] + w4[1] + w4[2] + w4[3]) / (float)B_N;
}

// ------------------------------------------------------------------ entry ----
extern "C" void kernel_launch(void* const* d_in, const int* in_sizes, int n_in,
                              void* d_out, int out_size, void* d_ws, size_t ws_size,
                              hipStream_t stream) {
    const float* outputs = (const float*)d_in[0];
    const float* labels  = (const float*)d_in[1];
    float* out = (float*)d_out;
    char* ws = (char*)d_ws;
    __hip_bfloat16* Obp = (__hip_bfloat16*)(ws);
    __hip_bfloat16* Lnp = (__hip_bfloat16*)(ws + 4194304);
    float* sq           = (float*)(ws + 6291456);
    float* pos_sums     = (float*)(ws + 6324224);
    float* neg_sums     = (float*)(ws + 6356992);
    unsigned* stats     = (unsigned*)(ws + 6389760);

    prep_kernel<<<B_N / 16, 256, 0, stream>>>(outputs, labels, Obp, Lnp, sq,
                                              pos_sums, neg_sums, stats);
    stats_kernel<<<NTRI, 256, 0, stream>>>((const short*)Lnp, (const short*)Obp,
                                           sq, stats);
    loss_kernel<<<NTRI, 256, 0, stream>>>((const short*)Lnp, (const short*)Obp,
                                          sq, stats, pos_sums, neg_sums);
    finalize_kernel<<<1, 256, 0, stream>>>(pos_sums, neg_sums, out);
}